// Round 1
// baseline (598.547 us; speedup 1.0000x reference)
//
#include <hip/hip_runtime.h>

namespace {
constexpr int T_N = 262144;   // number of times
constexpr int S_N = 512;      // weight columns
constexpr int K_N = 258;      // NUM_KNOTS + DEGREE - 1 (basis count / weight rows)
constexpr int NK  = 262;      // NUM_KNOTS + 2*DEGREE (knot vector length)
constexpr int ROWS = 64;      // rows per wave (lane r precomputes row0+r)
}

// Pre-kernel: per-row sums of weights (258 rows x 512 cols) -> d_ws.
__global__ void wsum_kernel(const float* __restrict__ W, float* __restrict__ wsum) {
    const int row  = blockIdx.x * 4 + (threadIdx.x >> 6);
    const int lane = threadIdx.x & 63;
    if (row >= K_N) return;
    const float* wr = W + (size_t)row * S_N;
    float s = 0.f;
#pragma unroll
    for (int c = 0; c < S_N / 64; ++c) s += wr[lane + c * 64];
#pragma unroll
    for (int off = 32; off > 0; off >>= 1) s += __shfl_xor(s, off, 64);
    if (lane == 0) wsum[row] = s;
}

// Phase A: lane r computes span + N0..N3 + out_sum for row0+r (all 64 rows of the
//          wave in parallel; the serial span-search/divide chain runs once, 64-wide).
// Phase B: pure streaming — per row: 1 broadcast ds_read_b128 (basis) + 32 FMA +
//          2 dwordx4 stores. Branch-free in the single-span case (~94% of waves).
__global__ __launch_bounds__(256) void bspline_kernel(
    const float* __restrict__ times,
    const float* __restrict__ W,
    const float* __restrict__ knots,
    const float* __restrict__ wsum,
    float* __restrict__ out,
    float* __restrict__ out_sum)
{
    __shared__ float  sk[NK];
    __shared__ float  sws[K_N];
    __shared__ float4 snf[4][ROWS];   // per-wave basis (N0..N3) per row
    __shared__ int    ssp[4][ROWS];   // per-wave span per row

    for (int idx = threadIdx.x; idx < NK;  idx += 256) sk[idx]  = knots[idx];
    for (int idx = threadIdx.x; idx < K_N; idx += 256) sws[idx] = wsum[idx];
    __syncthreads();

    const int wid  = threadIdx.x >> 6;
    const int lane = threadIdx.x & 63;
    const int row0 = (blockIdx.x * 4 + wid) * ROWS;

    const float k3    = sk[3];
    const float kend  = sk[NK - 4];               // knots[258] == times[-1]
    const float inv_h = 255.0f / (kend - k3);     // interior knots are linspace

    // ---------------- Phase A: per-lane precompute for row0+lane ----------------
    const int myrow = row0 + lane;
    const float t = times[myrow];

    int i;
    float N0, N1, N2, N3;
    if (t >= kend) {
        // Reference's half-open degree-0 indicator: t == last knot -> all-zero row.
        i = 257;
        N0 = N1 = N2 = N3 = 0.f;
    } else {
        // Span i: knots[i] <= t < knots[i+1], i in [3, 257].
        i = 3 + (int)((t - k3) * inv_h);
        i = i < 3 ? 3 : (i > 257 ? 257 : i);
        while (t <  sk[i])     --i;   // fixups: 0-1 steps (knots ~uniform)
        while (t >= sk[i + 1]) ++i;

        // Cox-de Boor (NURBS A2.2): N0..N3 = B_{i-3..i}(t). All denominators
        // contain the non-empty [k_i, k_{i+1}) -> nonzero, matching the
        // reference's drop-zero-denominator convention.
        const float left1  = t - sk[i];
        const float right1 = sk[i + 1] - t;
        const float left2  = t - sk[i - 1];
        const float right2 = sk[i + 2] - t;
        const float left3  = t - sk[i - 2];
        const float right3 = sk[i + 3] - t;
        float temp, saved;
        // j = 1
        temp = 1.0f / (right1 + left1);
        N0 = right1 * temp;
        N1 = left1 * temp;
        // j = 2
        temp = N0 / (right1 + left2);
        N0 = right1 * temp;
        saved = left2 * temp;
        temp = N1 / (right2 + left1);
        N1 = saved + right2 * temp;
        N2 = left1 * temp;
        // j = 3
        temp = N0 / (right1 + left3);
        N0 = right1 * temp;
        saved = left3 * temp;
        temp = N1 / (right2 + left2);
        N1 = saved + right2 * temp;
        saved = left2 * temp;
        temp = N2 / (right3 + left1);
        N2 = saved + right3 * temp;
        N3 = left1 * temp;
    }

    // out_sum: one coalesced 64-wide store — removed from the inner loop entirely.
    // (Same arithmetic/association as before: N dot wsum[i-3..i]; zero rows give 0.)
    out_sum[myrow] = N0 * sws[i - 3] + N1 * sws[i - 2] + N2 * sws[i - 1] + N3 * sws[i];

    snf[wid][lane] = make_float4(N0, N1, N2, N3);
    ssp[wid][lane] = i;
    // Same-wave LDS ops execute in order; compiler keeps write->read order
    // (may-alias) and inserts the lgkmcnt wait. No block barrier needed —
    // snf/ssp are private to this wave.

    // ---------------- Phase B: streaming stores ----------------
    const int colA = lane * 4;
    const int colB = colA + 256;
    float* op0 = out + (size_t)row0 * S_N;

    const int  i0  = __builtin_amdgcn_readfirstlane(i);
    const bool uni = __all(i == i0);

    if (uni) {
        // Single span for all 64 rows: load the 4 weight rows once,
        // then a branch-free, load-free (except broadcast ds_read) store loop.
        const float* wp = W + (size_t)(i0 - 3) * S_N;
        const float4 wA0 = *(const float4*)(wp + colA);
        const float4 wB0 = *(const float4*)(wp + colB);
        const float4 wA1 = *(const float4*)(wp + S_N + colA);
        const float4 wB1 = *(const float4*)(wp + S_N + colB);
        const float4 wA2 = *(const float4*)(wp + 2 * S_N + colA);
        const float4 wB2 = *(const float4*)(wp + 2 * S_N + colB);
        const float4 wA3 = *(const float4*)(wp + 3 * S_N + colA);
        const float4 wB3 = *(const float4*)(wp + 3 * S_N + colB);

#pragma unroll 4
        for (int r = 0; r < ROWS; ++r) {
            const float4 n = snf[wid][r];      // uniform addr -> broadcast read
            float* op = op0 + (size_t)r * S_N;
            float4 oa, ob;
            oa.x = n.x * wA0.x + n.y * wA1.x + n.z * wA2.x + n.w * wA3.x;
            oa.y = n.x * wA0.y + n.y * wA1.y + n.z * wA2.y + n.w * wA3.y;
            oa.z = n.x * wA0.z + n.y * wA1.z + n.z * wA2.z + n.w * wA3.z;
            oa.w = n.x * wA0.w + n.y * wA1.w + n.z * wA2.w + n.w * wA3.w;
            ob.x = n.x * wB0.x + n.y * wB1.x + n.z * wB2.x + n.w * wB3.x;
            ob.y = n.x * wB0.y + n.y * wB1.y + n.z * wB2.y + n.w * wB3.y;
            ob.z = n.x * wB0.z + n.y * wB1.z + n.z * wB2.z + n.w * wB3.z;
            ob.w = n.x * wB0.w + n.y * wB1.w + n.z * wB2.w + n.w * wB3.w;
            *(float4*)(op + colA) = oa;
            *(float4*)(op + colB) = ob;
        }
    } else {
        // Rare (~6% of waves): span changes inside the 64-row window.
        int span = -1;
        float4 wA0 = make_float4(0,0,0,0), wA1 = wA0, wA2 = wA0, wA3 = wA0;
        float4 wB0 = wA0, wB1 = wA0, wB2 = wA0, wB3 = wA0;
        for (int r = 0; r < ROWS; ++r) {
            const int ir = ssp[wid][r];        // uniform addr -> broadcast read
            if (ir != span) {                  // wave-uniform branch
                span = ir;
                const float* wp = W + (size_t)(ir - 3) * S_N;
                wA0 = *(const float4*)(wp + colA);
                wB0 = *(const float4*)(wp + colB);
                wA1 = *(const float4*)(wp + S_N + colA);
                wB1 = *(const float4*)(wp + S_N + colB);
                wA2 = *(const float4*)(wp + 2 * S_N + colA);
                wB2 = *(const float4*)(wp + 2 * S_N + colB);
                wA3 = *(const float4*)(wp + 3 * S_N + colA);
                wB3 = *(const float4*)(wp + 3 * S_N + colB);
            }
            const float4 n = snf[wid][r];
            float* op = op0 + (size_t)r * S_N;
            float4 oa, ob;
            oa.x = n.x * wA0.x + n.y * wA1.x + n.z * wA2.x + n.w * wA3.x;
            oa.y = n.x * wA0.y + n.y * wA1.y + n.z * wA2.y + n.w * wA3.y;
            oa.z = n.x * wA0.z + n.y * wA1.z + n.z * wA2.z + n.w * wA3.z;
            oa.w = n.x * wA0.w + n.y * wA1.w + n.z * wA2.w + n.w * wA3.w;
            ob.x = n.x * wB0.x + n.y * wB1.x + n.z * wB2.x + n.w * wB3.x;
            ob.y = n.x * wB0.y + n.y * wB1.y + n.z * wB2.y + n.w * wB3.y;
            ob.z = n.x * wB0.z + n.y * wB1.z + n.z * wB2.z + n.w * wB3.z;
            ob.w = n.x * wB0.w + n.y * wB1.w + n.z * wB2.w + n.w * wB3.w;
            *(float4*)(op + colA) = oa;
            *(float4*)(op + colB) = ob;
        }
    }
}

extern "C" void kernel_launch(void* const* d_in, const int* in_sizes, int n_in,
                              void* d_out, int out_size, void* d_ws, size_t ws_size,
                              hipStream_t stream) {
    const float* times = (const float*)d_in[0];
    const float* W     = (const float*)d_in[1];
    const float* knots = (const float*)d_in[2];
    float* out     = (float*)d_out;
    float* out_sum = out + (size_t)T_N * S_N;   // outputs concatenated flat
    float* wsum    = (float*)d_ws;              // 258 floats of scratch

    wsum_kernel<<<(K_N + 3) / 4, 256, 0, stream>>>(W, wsum);

    const int nblocks = T_N / (4 * ROWS);       // 1024 blocks, 4 waves each
    bspline_kernel<<<nblocks, 256, 0, stream>>>(times, W, knots, wsum, out, out_sum);
}

// Round 2
// 537.985 us; speedup vs baseline: 1.1126x; 1.1126x over previous
//
#include <hip/hip_runtime.h>

namespace {
constexpr int T_N = 262144;   // number of times
constexpr int S_N = 512;      // weight columns
constexpr int K_N = 258;      // NUM_KNOTS + DEGREE - 1 (basis count / weight rows)
constexpr int NK  = 262;      // NUM_KNOTS + 2*DEGREE (knot vector length)
constexpr int BLOCK_ROWS = 128;  // rows per block (4 waves x 32)
constexpr int WAVE_ROWS  = 32;   // rows streamed per wave
}

// Pre-kernel: per-row sums of weights (258 rows x 512 cols) -> d_ws.
__global__ void wsum_kernel(const float* __restrict__ W, float* __restrict__ wsum) {
    const int row  = blockIdx.x * 4 + (threadIdx.x >> 6);
    const int lane = threadIdx.x & 63;
    if (row >= K_N) return;
    const float* wr = W + (size_t)row * S_N;
    float s = 0.f;
#pragma unroll
    for (int c = 0; c < S_N / 64; ++c) s += wr[lane + c * 64];
#pragma unroll
    for (int off = 32; off > 0; off >>= 1) s += __shfl_xor(s, off, 64);
    if (lane == 0) wsum[row] = s;
}

// Phase A (block-cooperative): threads 0..127 each compute span + N0..N3 +
//   out_sum for one of the block's 128 rows -> LDS. Fully parallel; the serial
//   span-search/divide chain never appears in the streaming loop.
// Phase B (per wave, 32 rows): per row 1 broadcast LDS read + 32 FMA + 2
//   dwordx4 stores; weight rows reloaded only on (rare, wave-uniform) span
//   change. Single code path -> one set of 8 float4 weight regs -> low VGPR,
//   8192 waves resident for write-latency hiding.
__global__ __launch_bounds__(256) void bspline_kernel(
    const float* __restrict__ times,
    const float* __restrict__ W,
    const float* __restrict__ knots,
    const float* __restrict__ wsum,
    float* __restrict__ out,
    float* __restrict__ out_sum)
{
    __shared__ float  sk[NK];
    __shared__ float  sws[K_N];
    __shared__ float4 snf[BLOCK_ROWS];   // basis (N0..N3) per row
    __shared__ int    ssp[BLOCK_ROWS];   // span per row

    for (int idx = threadIdx.x; idx < NK;  idx += 256) sk[idx]  = knots[idx];
    for (int idx = threadIdx.x; idx < K_N; idx += 256) sws[idx] = wsum[idx];
    __syncthreads();

    const int tid  = threadIdx.x;
    const int row0 = blockIdx.x * BLOCK_ROWS;

    const float k3    = sk[3];
    const float kend  = sk[NK - 4];               // knots[258] == times[-1]
    const float inv_h = 255.0f / (kend - k3);     // interior knots are linspace

    // ---------------- Phase A ----------------
    if (tid < BLOCK_ROWS) {
        const int myrow = row0 + tid;
        const float t = times[myrow];

        int i;
        float N0, N1, N2, N3;
        if (t >= kend) {
            // Reference's half-open degree-0 indicator: t == last knot -> zero row.
            i = 257;
            N0 = N1 = N2 = N3 = 0.f;
        } else {
            // Span i: knots[i] <= t < knots[i+1], i in [3, 257].
            i = 3 + (int)((t - k3) * inv_h);
            i = i < 3 ? 3 : (i > 257 ? 257 : i);
            while (t <  sk[i])     --i;   // fixups: 0-1 steps (knots ~uniform)
            while (t >= sk[i + 1]) ++i;

            // Cox-de Boor (NURBS A2.2): N0..N3 = B_{i-3..i}(t). All denominators
            // contain the non-empty [k_i, k_{i+1}) -> nonzero, matching the
            // reference's drop-zero-denominator convention.
            const float left1  = t - sk[i];
            const float right1 = sk[i + 1] - t;
            const float left2  = t - sk[i - 1];
            const float right2 = sk[i + 2] - t;
            const float left3  = t - sk[i - 2];
            const float right3 = sk[i + 3] - t;
            float temp, saved;
            // j = 1
            temp = 1.0f / (right1 + left1);
            N0 = right1 * temp;
            N1 = left1 * temp;
            // j = 2
            temp = N0 / (right1 + left2);
            N0 = right1 * temp;
            saved = left2 * temp;
            temp = N1 / (right2 + left1);
            N1 = saved + right2 * temp;
            N2 = left1 * temp;
            // j = 3
            temp = N0 / (right1 + left3);
            N0 = right1 * temp;
            saved = left3 * temp;
            temp = N1 / (right2 + left2);
            N1 = saved + right2 * temp;
            saved = left2 * temp;
            temp = N2 / (right3 + left1);
            N2 = saved + right3 * temp;
            N3 = left1 * temp;
        }

        // out_sum: coalesced 128-wide store, removed from the streaming loop.
        out_sum[myrow] = N0 * sws[i - 3] + N1 * sws[i - 2] + N2 * sws[i - 1] + N3 * sws[i];

        snf[tid] = make_float4(N0, N1, N2, N3);
        ssp[tid] = i;
    }
    __syncthreads();

    // ---------------- Phase B: streaming stores ----------------
    const int wid  = tid >> 6;
    const int lane = tid & 63;
    const int colA = lane * 4;
    const int colB = colA + 256;
    const int rbase = wid * WAVE_ROWS;
    float* op0 = out + (size_t)(row0 + rbase) * S_N;

    int span = -12345;
    float4 wA0, wA1, wA2, wA3, wB0, wB1, wB2, wB3;
    wA0 = wA1 = wA2 = wA3 = wB0 = wB1 = wB2 = wB3 = make_float4(0.f, 0.f, 0.f, 0.f);

#pragma unroll 4
    for (int r = 0; r < WAVE_ROWS; ++r) {
        const int ir = ssp[rbase + r];        // uniform addr -> broadcast read
        if (ir != span) {                     // wave-uniform; ~1 taken per 32 rows
            span = ir;
            const float* wp = W + (size_t)(ir - 3) * S_N;
            wA0 = *(const float4*)(wp + colA);
            wB0 = *(const float4*)(wp + colB);
            wA1 = *(const float4*)(wp + S_N + colA);
            wB1 = *(const float4*)(wp + S_N + colB);
            wA2 = *(const float4*)(wp + 2 * S_N + colA);
            wB2 = *(const float4*)(wp + 2 * S_N + colB);
            wA3 = *(const float4*)(wp + 3 * S_N + colA);
            wB3 = *(const float4*)(wp + 3 * S_N + colB);
        }
        const float4 n = snf[rbase + r];      // uniform addr -> broadcast read
        float* op = op0 + (size_t)r * S_N;
        float4 oa, ob;
        oa.x = n.x * wA0.x + n.y * wA1.x + n.z * wA2.x + n.w * wA3.x;
        oa.y = n.x * wA0.y + n.y * wA1.y + n.z * wA2.y + n.w * wA3.y;
        oa.z = n.x * wA0.z + n.y * wA1.z + n.z * wA2.z + n.w * wA3.z;
        oa.w = n.x * wA0.w + n.y * wA1.w + n.z * wA2.w + n.w * wA3.w;
        ob.x = n.x * wB0.x + n.y * wB1.x + n.z * wB2.x + n.w * wB3.x;
        ob.y = n.x * wB0.y + n.y * wB1.y + n.z * wB2.y + n.w * wB3.y;
        ob.z = n.x * wB0.z + n.y * wB1.z + n.z * wB2.z + n.w * wB3.z;
        ob.w = n.x * wB0.w + n.y * wB1.w + n.z * wB2.w + n.w * wB3.w;
        *(float4*)(op + colA) = oa;
        *(float4*)(op + colB) = ob;
    }
}

extern "C" void kernel_launch(void* const* d_in, const int* in_sizes, int n_in,
                              void* d_out, int out_size, void* d_ws, size_t ws_size,
                              hipStream_t stream) {
    const float* times = (const float*)d_in[0];
    const float* W     = (const float*)d_in[1];
    const float* knots = (const float*)d_in[2];
    float* out     = (float*)d_out;
    float* out_sum = out + (size_t)T_N * S_N;   // outputs concatenated flat
    float* wsum    = (float*)d_ws;              // 258 floats of scratch

    wsum_kernel<<<(K_N + 3) / 4, 256, 0, stream>>>(W, wsum);

    const int nblocks = T_N / BLOCK_ROWS;       // 2048 blocks, 4 waves each
    bspline_kernel<<<nblocks, 256, 0, stream>>>(times, W, knots, wsum, out, out_sum);
}

// Round 3
// 530.517 us; speedup vs baseline: 1.1282x; 1.0141x over previous
//
#include <hip/hip_runtime.h>

namespace {
constexpr int T_N = 262144;   // number of times
constexpr int S_N = 512;      // weight columns
constexpr int K_N = 258;      // NUM_KNOTS + DEGREE - 1 (basis count / weight rows)
constexpr int NK  = 262;      // NUM_KNOTS + 2*DEGREE (knot vector length)
constexpr int BLOCK_ROWS = 128;  // rows per block (4 waves x 32)
constexpr int WAVE_ROWS  = 32;   // rows streamed per wave
}

// Pre-kernel: per-row sums of weights (258 rows x 512 cols) -> d_ws.
__global__ void wsum_kernel(const float* __restrict__ W, float* __restrict__ wsum) {
    const int row  = blockIdx.x * 4 + (threadIdx.x >> 6);
    const int lane = threadIdx.x & 63;
    if (row >= K_N) return;
    const float* wr = W + (size_t)row * S_N;
    float s = 0.f;
#pragma unroll
    for (int c = 0; c < S_N / 64; ++c) s += wr[lane + c * 64];
#pragma unroll
    for (int off = 32; off > 0; off >>= 1) s += __shfl_xor(s, off, 64);
    if (lane == 0) wsum[row] = s;
}

// Phase A (block-cooperative): threads 0..127 each compute span + N0..N3 +
//   out_sum for one of the block's 128 rows -> LDS.
// Phase B (per wave, 32 rows): segment the rows by span ONCE via __ballot
//   (spans are monotone over sorted times; almost always 1 segment), then a
//   completely branch-free streaming loop per segment:
//   per row = 1 broadcast ds_read_b128 + 32 FMA + 2 dwordx4 stores.
//   No per-row branch -> compiler batches ds_reads and keeps stores in flight
//   back-to-back (fill-kernel-style), instead of fencing at every iteration.
__global__ __launch_bounds__(256) void bspline_kernel(
    const float* __restrict__ times,
    const float* __restrict__ W,
    const float* __restrict__ knots,
    const float* __restrict__ wsum,
    float* __restrict__ out,
    float* __restrict__ out_sum)
{
    __shared__ float  sk[NK];
    __shared__ float  sws[K_N];
    __shared__ float4 snf[BLOCK_ROWS];   // basis (N0..N3) per row
    __shared__ int    ssp[BLOCK_ROWS];   // span per row

    for (int idx = threadIdx.x; idx < NK;  idx += 256) sk[idx]  = knots[idx];
    for (int idx = threadIdx.x; idx < K_N; idx += 256) sws[idx] = wsum[idx];
    __syncthreads();

    const int tid  = threadIdx.x;
    const int row0 = blockIdx.x * BLOCK_ROWS;

    const float k3    = sk[3];
    const float kend  = sk[NK - 4];               // knots[258] == times[-1]
    const float inv_h = 255.0f / (kend - k3);     // interior knots are linspace

    // ---------------- Phase A ----------------
    if (tid < BLOCK_ROWS) {
        const int myrow = row0 + tid;
        const float t = times[myrow];

        int i;
        float N0, N1, N2, N3;
        if (t >= kend) {
            // Reference's half-open degree-0 indicator: t == last knot -> zero row.
            // Span 257 with N=0 flows through the normal streaming path.
            i = 257;
            N0 = N1 = N2 = N3 = 0.f;
        } else {
            // Span i: knots[i] <= t < knots[i+1], i in [3, 257].
            i = 3 + (int)((t - k3) * inv_h);
            i = i < 3 ? 3 : (i > 257 ? 257 : i);
            while (t <  sk[i])     --i;   // fixups: 0-1 steps (knots ~uniform)
            while (t >= sk[i + 1]) ++i;

            // Cox-de Boor (NURBS A2.2): N0..N3 = B_{i-3..i}(t). All denominators
            // contain the non-empty [k_i, k_{i+1}) -> nonzero, matching the
            // reference's drop-zero-denominator convention.
            const float left1  = t - sk[i];
            const float right1 = sk[i + 1] - t;
            const float left2  = t - sk[i - 1];
            const float right2 = sk[i + 2] - t;
            const float left3  = t - sk[i - 2];
            const float right3 = sk[i + 3] - t;
            float temp, saved;
            // j = 1
            temp = 1.0f / (right1 + left1);
            N0 = right1 * temp;
            N1 = left1 * temp;
            // j = 2
            temp = N0 / (right1 + left2);
            N0 = right1 * temp;
            saved = left2 * temp;
            temp = N1 / (right2 + left1);
            N1 = saved + right2 * temp;
            N2 = left1 * temp;
            // j = 3
            temp = N0 / (right1 + left3);
            N0 = right1 * temp;
            saved = left3 * temp;
            temp = N1 / (right2 + left2);
            N1 = saved + right2 * temp;
            saved = left2 * temp;
            temp = N2 / (right3 + left1);
            N2 = saved + right3 * temp;
            N3 = left1 * temp;
        }

        // out_sum: coalesced 128-wide store, removed from the streaming loop.
        out_sum[myrow] = N0 * sws[i - 3] + N1 * sws[i - 2] + N2 * sws[i - 1] + N3 * sws[i];

        snf[tid] = make_float4(N0, N1, N2, N3);
        ssp[tid] = i;
    }
    __syncthreads();

    // ---------------- Phase B: branch-free segmented streaming ----------------
    const int wid   = tid >> 6;
    const int lane  = tid & 63;
    const int colA  = lane * 4;
    const int colB  = colA + 256;
    const int rbase = wid * WAVE_ROWS;
    float* const op0 = out + (size_t)(row0 + rbase) * S_N;

    // Lane l holds span of row (l & 31); LDS read is 2-way same-address
    // broadcast per bank -> conflict-free.
    const int spl = ssp[rbase + (lane & 31)];

    int r = 0;
    while (r < WAVE_ROWS) {
        const int s_cur = __shfl(spl, r, 64);           // wave-uniform span of row r
        unsigned long long diff = __ballot(spl != s_cur);
        diff &= (0xFFFFFFFFull << r) & 0xFFFFFFFFull;   // rows >= r, low copy only
        const int e = diff ? (int)__builtin_ctzll(diff) : WAVE_ROWS;

        // Load the 4 weight rows for this span (L2-resident after first touch).
        const float* wp = W + (size_t)(s_cur - 3) * S_N;
        const float4 wA0 = *(const float4*)(wp + colA);
        const float4 wB0 = *(const float4*)(wp + colB);
        const float4 wA1 = *(const float4*)(wp + S_N + colA);
        const float4 wB1 = *(const float4*)(wp + S_N + colB);
        const float4 wA2 = *(const float4*)(wp + 2 * S_N + colA);
        const float4 wB2 = *(const float4*)(wp + 2 * S_N + colB);
        const float4 wA3 = *(const float4*)(wp + 3 * S_N + colA);
        const float4 wB3 = *(const float4*)(wp + 3 * S_N + colB);

        float* op = op0 + (size_t)r * S_N;
#pragma unroll 4
        for (int rr = r; rr < e; ++rr, op += S_N) {
            const float4 n = snf[rbase + rr];   // uniform addr -> broadcast read
            float4 oa, ob;
            oa.x = n.x * wA0.x + n.y * wA1.x + n.z * wA2.x + n.w * wA3.x;
            oa.y = n.x * wA0.y + n.y * wA1.y + n.z * wA2.y + n.w * wA3.y;
            oa.z = n.x * wA0.z + n.y * wA1.z + n.z * wA2.z + n.w * wA3.z;
            oa.w = n.x * wA0.w + n.y * wA1.w + n.z * wA2.w + n.w * wA3.w;
            ob.x = n.x * wB0.x + n.y * wB1.x + n.z * wB2.x + n.w * wB3.x;
            ob.y = n.x * wB0.y + n.y * wB1.y + n.z * wB2.y + n.w * wB3.y;
            ob.z = n.x * wB0.z + n.y * wB1.z + n.z * wB2.z + n.w * wB3.z;
            ob.w = n.x * wB0.w + n.y * wB1.w + n.z * wB2.w + n.w * wB3.w;
            *(float4*)(op + colA) = oa;
            *(float4*)(op + colB) = ob;
        }
        r = e;
    }
}

extern "C" void kernel_launch(void* const* d_in, const int* in_sizes, int n_in,
                              void* d_out, int out_size, void* d_ws, size_t ws_size,
                              hipStream_t stream) {
    const float* times = (const float*)d_in[0];
    const float* W     = (const float*)d_in[1];
    const float* knots = (const float*)d_in[2];
    float* out     = (float*)d_out;
    float* out_sum = out + (size_t)T_N * S_N;   // outputs concatenated flat
    float* wsum    = (float*)d_ws;              // 258 floats of scratch

    wsum_kernel<<<(K_N + 3) / 4, 256, 0, stream>>>(W, wsum);

    const int nblocks = T_N / BLOCK_ROWS;       // 2048 blocks, 4 waves each
    bspline_kernel<<<nblocks, 256, 0, stream>>>(times, W, knots, wsum, out, out_sum);
}